// Round 6
// baseline (379.307 us; speedup 1.0000x reference)
//
#include <hip/hip_runtime.h>
#include <math.h>

#define T_DIM 8192
#define B_DIM 4
#define INDIM 512
#define DV 512
#define DK 64
#define CHUNK 128
#define NCH (T_DIM / CHUNK)     // 64
#define ROWS (T_DIM * B_DIM)    // 32768
#define NPAD 768                // 704 proj cols padded to 6x128
#define KCAT 192                // 128 intra + 64 state
#define EPSF 1e-8f

typedef float float4_t __attribute__((ext_vector_type(4)));
typedef short short8_t __attribute__((ext_vector_type(8)));

__device__ inline unsigned short f2bf(float f) {
  unsigned int u = __float_as_uint(f);
  unsigned int r = (u + 0x7fffu + ((u >> 16) & 1u)) >> 16;
  return (unsigned short)r;
}
__device__ inline float bf2f(unsigned short h) {
  return __uint_as_float(((unsigned int)h) << 16);
}

__device__ inline void gload16(const void* g, void* l) {
  __builtin_amdgcn_global_load_lds(
      (const __attribute__((address_space(1))) void*)g,
      (__attribute__((address_space(3))) void*)l, 16, 0, 0);
}

// ---------------------------------------------------------------------------
// C0: merged split-cast.  blocks [0,16384): x -> xh/xl.
// blocks [16384,16768): padded concat weights -> wh/wl + bcat.
// ---------------------------------------------------------------------------
__global__ __launch_bounds__(256) void cast_kernel(
    const float* __restrict__ x,
    const float* __restrict__ Wv, const float* __restrict__ Wk,
    const float* __restrict__ Wq, const float* __restrict__ Wa,
    const float* __restrict__ bv, const float* __restrict__ bk,
    const float* __restrict__ bq, const float* __restrict__ ba,
    unsigned short* __restrict__ xh, unsigned short* __restrict__ xl,
    unsigned short* __restrict__ wh, unsigned short* __restrict__ wl,
    float* __restrict__ bcat)
{
  if (blockIdx.x < 16384) {
    const size_t i4 = ((size_t)blockIdx.x * 256 + threadIdx.x) * 4;
    const float4 v = *(const float4*)&x[i4];
    ushort4 h, l;
    h.x = f2bf(v.x); l.x = f2bf(v.x - bf2f(h.x));
    h.y = f2bf(v.y); l.y = f2bf(v.y - bf2f(h.y));
    h.z = f2bf(v.z); l.z = f2bf(v.z - bf2f(h.z));
    h.w = f2bf(v.w); l.w = f2bf(v.w - bf2f(h.w));
    *(ushort4*)&xh[i4] = h;
    *(ushort4*)&xl[i4] = l;
  } else {
    const int t = (blockIdx.x - 16384) * 256 + threadIdx.x;
    const size_t i4 = (size_t)t * 4;
    const int row = (int)(i4 >> 9);
    const int col = (int)(i4 & 511);
    float4 v = {0.f, 0.f, 0.f, 0.f};
    if (row < 512)      v = *(const float4*)&Wv[(size_t)row * INDIM + col];
    else if (row < 576) v = *(const float4*)&Wk[(size_t)(row - 512) * INDIM + col];
    else if (row < 640) v = *(const float4*)&Wq[(size_t)(row - 576) * INDIM + col];
    else if (row < 704) v = *(const float4*)&Wa[(size_t)(row - 640) * INDIM + col];
    ushort4 h, l;
    h.x = f2bf(v.x); l.x = f2bf(v.x - bf2f(h.x));
    h.y = f2bf(v.y); l.y = f2bf(v.y - bf2f(h.y));
    h.z = f2bf(v.z); l.z = f2bf(v.z - bf2f(h.z));
    h.w = f2bf(v.w); l.w = f2bf(v.w - bf2f(h.w));
    *(ushort4*)&wh[i4] = h;
    *(ushort4*)&wl[i4] = l;
    if (t < NPAD) {
      float b = 0.f;
      if (t < 512)      b = bv[t];
      else if (t < 576) b = bk[t - 512];
      else if (t < 640) b = bq[t - 576];
      else if (t < 704) b = ba[t - 640];
      bcat[t] = b;
    }
  }
}

// ---------------------------------------------------------------------------
// K1: split-bf16 MFMA projection GEMM (M=32768,K=512,N=768), fused epilogue.
// v -> Bt hi/lo DIRECTLY TRANSPOSED [cb][d][s] (vt_kernel eliminated);
// k -> k_ws fp32; q -> Acat cols [128,192) bf16 hi/lo; alpha -> a_ws (sigmoid).
// ---------------------------------------------------------------------------
__global__ __launch_bounds__(256) void proj_mfma_kernel(
    const unsigned short* __restrict__ xh, const unsigned short* __restrict__ xl,
    const unsigned short* __restrict__ wh, const unsigned short* __restrict__ wl,
    const float* __restrict__ bcat,
    unsigned short* __restrict__ Bt_h, unsigned short* __restrict__ Bt_l,
    float* __restrict__ k_ws,
    unsigned short* __restrict__ Acat_h, unsigned short* __restrict__ Acat_l,
    float* __restrict__ a_ws)
{
  __shared__ __align__(16) unsigned short Ah[128 * 32];
  __shared__ __align__(16) unsigned short Al[128 * 32];
  __shared__ __align__(16) unsigned short Bh[128 * 32];
  __shared__ __align__(16) unsigned short Bl[128 * 32];

  const int tid  = threadIdx.x;
  const int r0   = blockIdx.x * 128;
  const int c0   = blockIdx.y * 128;
  const int wave = tid >> 6, lane = tid & 63;
  const int wm   = (wave & 1) * 64, wn = (wave >> 1) * 64;
  const int fm   = lane & 15;
  const int fk   = (lane >> 4) * 8;

  float4_t acc[4][4];
#pragma unroll
  for (int i = 0; i < 4; ++i)
#pragma unroll
    for (int j = 0; j < 4; ++j) acc[i][j] = (float4_t)0.0f;

  const int srow = tid >> 2;
  const int scol = (tid & 3) * 8;

  for (int k0 = 0; k0 < INDIM; k0 += 32) {
    const size_t ga0 = (size_t)(r0 + srow) * INDIM + k0 + scol;
    const size_t ga1 = (size_t)(r0 + 64 + srow) * INDIM + k0 + scol;
    const size_t gb0 = (size_t)(c0 + srow) * INDIM + k0 + scol;
    const size_t gb1 = (size_t)(c0 + 64 + srow) * INDIM + k0 + scol;
    gload16(&xh[ga0], &Ah[tid * 8]);
    gload16(&xh[ga1], &Ah[(256 + tid) * 8]);
    gload16(&xl[ga0], &Al[tid * 8]);
    gload16(&xl[ga1], &Al[(256 + tid) * 8]);
    gload16(&wh[gb0], &Bh[tid * 8]);
    gload16(&wh[gb1], &Bh[(256 + tid) * 8]);
    gload16(&wl[gb0], &Bl[tid * 8]);
    gload16(&wl[gb1], &Bl[(256 + tid) * 8]);
    __syncthreads();

    short8_t a_hi[4], a_lo[4], b_hi[4], b_lo[4];
#pragma unroll
    for (int i = 0; i < 4; ++i) {
      const int ar = (wm + i * 16 + fm) * 32 + fk;
      a_hi[i] = *(const short8_t*)&Ah[ar];
      a_lo[i] = *(const short8_t*)&Al[ar];
    }
#pragma unroll
    for (int j = 0; j < 4; ++j) {
      const int br = (wn + j * 16 + fm) * 32 + fk;
      b_hi[j] = *(const short8_t*)&Bh[br];
      b_lo[j] = *(const short8_t*)&Bl[br];
    }
#pragma unroll
    for (int i = 0; i < 4; ++i)
#pragma unroll
      for (int j = 0; j < 4; ++j) {
        acc[i][j] = __builtin_amdgcn_mfma_f32_16x16x32_bf16(a_hi[i], b_hi[j], acc[i][j], 0, 0, 0);
        acc[i][j] = __builtin_amdgcn_mfma_f32_16x16x32_bf16(a_lo[i], b_hi[j], acc[i][j], 0, 0, 0);
        acc[i][j] = __builtin_amdgcn_mfma_f32_16x16x32_bf16(a_hi[i], b_lo[j], acc[i][j], 0, 0, 0);
      }
    __syncthreads();
  }

#pragma unroll
  for (int j = 0; j < 4; ++j) {
    const int col = c0 + wn + j * 16 + fm;
    if (col >= 704) continue;
    const float bias = bcat[col];
#pragma unroll
    for (int i = 0; i < 4; ++i) {
#pragma unroll
      for (int r = 0; r < 4; ++r) {
        const int row = r0 + wm + i * 16 + (lane >> 4) * 4 + r;  // row = t*4+b
        const float val = acc[i][j][r] + bias;
        if (col < 512) {
          // v in transposed split-bf16 layout Bt[cb][d][s]
          const int tg = row >> 2, bb = row & 3;
          const int cc = tg >> 7, sl = tg & 127;
          const size_t va = ((size_t)(cc * 4 + bb) * DV + col) * CHUNK + sl;
          const unsigned short h = f2bf(val);
          Bt_h[va] = h;
          Bt_l[va] = f2bf(val - bf2f(h));
        } else if (col < 576) {
          k_ws[(size_t)row * DK + col - 512] = val;
        } else if (col < 640) {
          const int tg = row >> 2, bb = row & 3;
          const int cc = tg >> 7, tl = tg & 127;
          const size_t qa = ((size_t)(cc * 4 + bb) * 128 + tl) * KCAT + 128 + (col - 576);
          const unsigned short h = f2bf(val);
          Acat_h[qa] = h;
          Acat_l[qa] = f2bf(val - bf2f(h));
        } else {
          a_ws[(size_t)row * DK + col - 640] = 1.0f / (1.0f + expf(-val));
        }
      }
    }
  }
}

// ---------------------------------------------------------------------------
// K2: per-(c,b) chunk prep.  LDS-resident cumprod, then coalesced
// q_t (Acat hi/lo RMW) and k_t (k_ws fp32 RMW) passes.  grid (NCH, B_DIM).
// ---------------------------------------------------------------------------
__global__ __launch_bounds__(256) void prep_kernel(
    const float* __restrict__ a_ws, float* __restrict__ k_ws,
    unsigned short* __restrict__ Acat_h, unsigned short* __restrict__ Acat_l,
    float* __restrict__ pend)
{
  __shared__ float pal[CHUNK][DK];    // 32 KB: alpha -> cumprod p
  const int c = blockIdx.x, b = blockIdx.y;
  const int cb = c * B_DIM + b;
  const int tid = threadIdx.x;

#pragma unroll
  for (int i = 0; i < 8; ++i) {
    const int f = (i * 256 + tid) * 4;       // 0..8191
    const int t = f >> 6, n0 = f & 63;
    const float4 av = *(const float4*)&a_ws[(size_t)(c * CHUNK + t) * 256 + b * 64 + n0];
    *(float4*)&pal[t][n0] = av;
  }
  __syncthreads();

  if (tid < 64) {
    float p = 1.0f;
#pragma unroll 4
    for (int t = 0; t < CHUNK; ++t) {
      p *= fmaxf(pal[t][tid], EPSF);
      pal[t][tid] = p;
    }
    pend[c * 256 + b * 64 + tid] = p;
  }
  __syncthreads();

#pragma unroll
  for (int i = 0; i < 8; ++i) {
    const int f = (i * 256 + tid) * 4;
    const int t = f >> 6, n0 = f & 63;
    const size_t qa = ((size_t)cb * CHUNK + t) * KCAT + 128 + n0;
    ushort4 qh = *(const ushort4*)&Acat_h[qa];
    ushort4 ql = *(const ushort4*)&Acat_l[qa];
    float q0 = (bf2f(qh.x) + bf2f(ql.x)) * pal[t][n0 + 0];
    float q1 = (bf2f(qh.y) + bf2f(ql.y)) * pal[t][n0 + 1];
    float q2 = (bf2f(qh.z) + bf2f(ql.z)) * pal[t][n0 + 2];
    float q3 = (bf2f(qh.w) + bf2f(ql.w)) * pal[t][n0 + 3];
    ushort4 h, l;
    h.x = f2bf(q0); l.x = f2bf(q0 - bf2f(h.x));
    h.y = f2bf(q1); l.y = f2bf(q1 - bf2f(h.y));
    h.z = f2bf(q2); l.z = f2bf(q2 - bf2f(h.z));
    h.w = f2bf(q3); l.w = f2bf(q3 - bf2f(h.w));
    *(ushort4*)&Acat_h[qa] = h;
    *(ushort4*)&Acat_l[qa] = l;
  }

#pragma unroll
  for (int i = 0; i < 8; ++i) {
    const int f = (i * 256 + tid) * 4;
    const int t = f >> 6, n0 = f & 63;
    const size_t ka = (size_t)(c * CHUNK + t) * 256 + b * 64 + n0;
    float4 kv = *(const float4*)&k_ws[ka];
    kv.x = kv.x / (pal[t][n0 + 0] + EPSF);
    kv.y = kv.y / (pal[t][n0 + 1] + EPSF);
    kv.z = kv.z / (pal[t][n0 + 2] + EPSF);
    kv.w = kv.w / (pal[t][n0 + 3] + EPSF);
    *(float4*)&k_ws[ka] = kv;
  }
}

// ---------------------------------------------------------------------------
// K3: wchunk via MFMA.  W[d][n] = (sum_t v^T[d][t]*k_t[t][n]) * pend[n].
// ---------------------------------------------------------------------------
__global__ __launch_bounds__(256) void wchunk_mfma_kernel(
    const unsigned short* __restrict__ Bt_h, const unsigned short* __restrict__ Bt_l,
    const float* __restrict__ k_ws, const float* __restrict__ pend,
    float* __restrict__ W_ws)
{
  __shared__ __align__(16) unsigned short Ah[128 * 32];
  __shared__ __align__(16) unsigned short Al[128 * 32];

  const int c = blockIdx.x, b = blockIdx.y, dt = blockIdx.z;
  const int cb = c * B_DIM + b;
  const int tid  = threadIdx.x;
  const int wave = tid >> 6, lane = tid & 63;
  const int wm   = (wave & 1) * 64;
  const int wn   = (wave >> 1) * 32;
  const int fm   = lane & 15;
  const int fk   = (lane >> 4) * 8;

  const unsigned short* Ab_h = Bt_h + ((size_t)cb * DV + dt * 128) * CHUNK;
  const unsigned short* Ab_l = Bt_l + ((size_t)cb * DV + dt * 128) * CHUNK;

  float4_t acc[4][2];
#pragma unroll
  for (int i = 0; i < 4; ++i)
#pragma unroll
    for (int j = 0; j < 2; ++j) acc[i][j] = (float4_t)0.0f;

  for (int ks = 0; ks < 4; ++ks) {
    const int k0 = ks * 32;
#pragma unroll
    for (int q = 0; q < 2; ++q) {
      const int flat = (q * 256 + tid) * 8;
      const int row = flat >> 5, col = flat & 31;
      gload16(&Ab_h[(size_t)row * CHUNK + k0 + col], &Ah[flat]);
      gload16(&Ab_l[(size_t)row * CHUNK + k0 + col], &Al[flat]);
    }

    short8_t b_hi[2], b_lo[2];
#pragma unroll
    for (int j = 0; j < 2; ++j) {
      const int n = wn + j * 16 + fm;
#pragma unroll
      for (int e = 0; e < 8; ++e) {
        const float kv = k_ws[(size_t)(c * CHUNK + k0 + fk + e) * 256 + b * 64 + n];
        const unsigned short h = f2bf(kv);
        b_hi[j][e] = (short)h;
        b_lo[j][e] = (short)f2bf(kv - bf2f(h));
      }
    }
    __syncthreads();

    short8_t a_hi[4], a_lo[4];
#pragma unroll
    for (int i = 0; i < 4; ++i) {
      const int ar = (wm + i * 16 + fm) * 32 + fk;
      a_hi[i] = *(const short8_t*)&Ah[ar];
      a_lo[i] = *(const short8_t*)&Al[ar];
    }
#pragma unroll
    for (int i = 0; i < 4; ++i)
#pragma unroll
      for (int j = 0; j < 2; ++j) {
        acc[i][j] = __builtin_amdgcn_mfma_f32_16x16x32_bf16(a_hi[i], b_hi[j], acc[i][j], 0, 0, 0);
        acc[i][j] = __builtin_amdgcn_mfma_f32_16x16x32_bf16(a_lo[i], b_hi[j], acc[i][j], 0, 0, 0);
        acc[i][j] = __builtin_amdgcn_mfma_f32_16x16x32_bf16(a_hi[i], b_lo[j], acc[i][j], 0, 0, 0);
      }
    __syncthreads();
  }

#pragma unroll
  for (int j = 0; j < 2; ++j) {
    const int n = wn + j * 16 + fm;
    const float pj = pend[c * 256 + b * 64 + n];
#pragma unroll
    for (int i = 0; i < 4; ++i) {
#pragma unroll
      for (int r = 0; r < 4; ++r) {
        const int d = dt * 128 + wm + i * 16 + (lane >> 4) * 4 + r;
        W_ws[((size_t)cb * DV + d) * DK + n] = acc[i][j][r] * pj;
      }
    }
  }
}

// ---------------------------------------------------------------------------
// K4: sequential state scan over chunks (in place; W_ws[c] <- S_c pre-update)
// ---------------------------------------------------------------------------
__global__ __launch_bounds__(256) void scan_kernel(
    float* __restrict__ W_ws, const float* __restrict__ pend)
{
  const int flat = blockIdx.x * 256 + threadIdx.x;
  const int n = flat & 63;
  const int bd = flat >> 6;
  const int b = bd >> 9;
  float s = 0.0f;
  for (int c = 0; c < NCH; ++c) {
    const int off = c * 131072 + flat;
    const float w = W_ws[off];
    W_ws[off] = s;
    s = s * pend[c * 256 + b * 64 + n] + w;
  }
}

// ---------------------------------------------------------------------------
// K5: A = tril(q_t @ k_t^T) via MFMA.  Writes Acat cols [0,128) hi/lo.
// ---------------------------------------------------------------------------
__global__ __launch_bounds__(256) void score_mfma_kernel(
    const float* __restrict__ k_ws,
    unsigned short* __restrict__ Acat_h, unsigned short* __restrict__ Acat_l)
{
  __shared__ __align__(16) unsigned short Ah[128 * 32];
  __shared__ __align__(16) unsigned short Al[128 * 32];
  __shared__ __align__(16) unsigned short Bh[128 * 32];
  __shared__ __align__(16) unsigned short Bl[128 * 32];

  const int c = blockIdx.x, b = blockIdx.y;
  const int cb = c * B_DIM + b;
  const int tid  = threadIdx.x;
  const int wave = tid >> 6, lane = tid & 63;
  const int wm   = (wave & 1) * 64, wn = (wave >> 1) * 64;
  const int fm   = lane & 15;
  const int fk   = (lane >> 4) * 8;

  const unsigned short* Aq_h = Acat_h + (size_t)cb * CHUNK * KCAT + 128;
  const unsigned short* Aq_l = Acat_l + (size_t)cb * CHUNK * KCAT + 128;

  float4_t acc[4][4];
#pragma unroll
  for (int i = 0; i < 4; ++i)
#pragma unroll
    for (int j = 0; j < 4; ++j) acc[i][j] = (float4_t)0.0f;

  for (int ks = 0; ks < 2; ++ks) {
    const int k0 = ks * 32;
#pragma unroll
    for (int q = 0; q < 2; ++q) {
      const int flat = (q * 256 + tid) * 8;
      const int row = flat >> 5, col = flat & 31;
      gload16(&Aq_h[(size_t)row * KCAT + k0 + col], &Ah[flat]);
      gload16(&Aq_l[(size_t)row * KCAT + k0 + col], &Al[flat]);
    }
#pragma unroll
    for (int q = 0; q < 4; ++q) {
      const int flat = (q * 256 + tid) * 4;
      const int s = flat >> 5, n0 = flat & 31;
      const float4 kv = *(const float4*)&k_ws[(size_t)(c * CHUNK + s) * 256 + b * 64 + k0 + n0];
      ushort4 h, l;
      h.x = f2bf(kv.x); l.x = f2bf(kv.x - bf2f(h.x));
      h.y = f2bf(kv.y); l.y = f2bf(kv.y - bf2f(h.y));
      h.z = f2bf(kv.z); l.z = f2bf(kv.z - bf2f(h.z));
      h.w = f2bf(kv.w); l.w = f2bf(kv.w - bf2f(h.w));
      *(ushort4*)&Bh[s * 32 + n0] = h;
      *(ushort4*)&Bl[s * 32 + n0] = l;
    }
    __syncthreads();

    short8_t a_hi[4], a_lo[4], b_hi[4], b_lo[4];
#pragma unroll
    for (int i = 0; i < 4; ++i) {
      const int ar = (wm + i * 16 + fm) * 32 + fk;
      a_hi[i] = *(const short8_t*)&Ah[ar];
      a_lo[i] = *(const short8_t*)&Al[ar];
    }
#pragma unroll
    for (int j = 0; j < 4; ++j) {
      const int br = (wn + j * 16 + fm) * 32 + fk;
      b_hi[j] = *(const short8_t*)&Bh[br];
      b_lo[j] = *(const short8_t*)&Bl[br];
    }
#pragma unroll
    for (int i = 0; i < 4; ++i)
#pragma unroll
      for (int j = 0; j < 4; ++j) {
        acc[i][j] = __builtin_amdgcn_mfma_f32_16x16x32_bf16(a_hi[i], b_hi[j], acc[i][j], 0, 0, 0);
        acc[i][j] = __builtin_amdgcn_mfma_f32_16x16x32_bf16(a_lo[i], b_hi[j], acc[i][j], 0, 0, 0);
        acc[i][j] = __builtin_amdgcn_mfma_f32_16x16x32_bf16(a_hi[i], b_lo[j], acc[i][j], 0, 0, 0);
      }
    __syncthreads();
  }

#pragma unroll
  for (int j = 0; j < 4; ++j) {
    const int s = wn + j * 16 + fm;
#pragma unroll
    for (int i = 0; i < 4; ++i) {
#pragma unroll
      for (int r = 0; r < 4; ++r) {
        const int t = wm + i * 16 + (lane >> 4) * 4 + r;
        const float vv = (s <= t) ? acc[i][j][r] : 0.0f;
        const unsigned short h = f2bf(vv);
        const size_t oa = ((size_t)cb * CHUNK + t) * KCAT + s;
        Acat_h[oa] = h;
        Acat_l[oa] = f2bf(vv - bf2f(h));
      }
    }
  }
}

// ---------------------------------------------------------------------------
// K6: y = [A|q_t] @ [v ; S^T]  via split-bf16 MFMA.  M=128(t) N=128(d-tile)
// K=192.  Steps 0..3 stage B from Bt; steps 4,5 convert S fp32.
// ---------------------------------------------------------------------------
__global__ __launch_bounds__(256) void out_mfma_kernel(
    const unsigned short* __restrict__ Acat_h, const unsigned short* __restrict__ Acat_l,
    const unsigned short* __restrict__ Bt_h, const unsigned short* __restrict__ Bt_l,
    const float* __restrict__ W_ws, float* __restrict__ out)
{
  __shared__ __align__(16) unsigned short Ah[128 * 32];
  __shared__ __align__(16) unsigned short Al[128 * 32];
  __shared__ __align__(16) unsigned short Bh[128 * 32];
  __shared__ __align__(16) unsigned short Bl[128 * 32];

  const int c = blockIdx.x, b = blockIdx.y, nt = blockIdx.z;
  const int cb = c * B_DIM + b;
  const int tid  = threadIdx.x;
  const int wave = tid >> 6, lane = tid & 63;
  const int wm   = (wave & 1) * 64, wn = (wave >> 1) * 64;
  const int fm   = lane & 15;
  const int fk   = (lane >> 4) * 8;

  const unsigned short* Ab_h = Acat_h + (size_t)cb * CHUNK * KCAT;
  const unsigned short* Ab_l = Acat_l + (size_t)cb * CHUNK * KCAT;
  const unsigned short* Bb_h = Bt_h + ((size_t)cb * DV + nt * 128) * CHUNK;
  const unsigned short* Bb_l = Bt_l + ((size_t)cb * DV + nt * 128) * CHUNK;
  const float* Sb = W_ws + ((size_t)cb * DV + nt * 128) * DK;

  float4_t acc[4][4];
#pragma unroll
  for (int i = 0; i < 4; ++i)
#pragma unroll
    for (int j = 0; j < 4; ++j) acc[i][j] = (float4_t)0.0f;

  for (int ks = 0; ks < 6; ++ks) {
    const int k0 = ks * 32;
#pragma unroll
    for (int q = 0; q < 2; ++q) {
      const int flat = q * 2048 + tid * 8;
      const int row = flat >> 5, col = flat & 31;
      gload16(&Ab_h[(size_t)row * KCAT + k0 + col], &Ah[flat]);
      gload16(&Ab_l[(size_t)row * KCAT + k0 + col], &Al[flat]);
    }
    if (ks < 4) {
#pragma unroll
      for (int q = 0; q < 2; ++q) {
        const int flat = q * 2048 + tid * 8;
        const int row = flat >> 5, col = flat & 31;
        gload16(&Bb_h[(size_t)row * CHUNK + k0 + col], &Bh[flat]);
        gload16(&Bb_l[(size_t)row * CHUNK + k0 + col], &Bl[flat]);
      }
    } else {
#pragma unroll
      for (int q = 0; q < 4; ++q) {
        const int flat = (q * 256 + tid) * 4;
        const int r = flat >> 5, n0 = flat & 31;
        const float4 sv = *(const float4*)&Sb[(size_t)r * DK + (k0 - 128) + n0];
        ushort4 h, l;
        h.x = f2bf(sv.x); l.x = f2bf(sv.x - bf2f(h.x));
        h.y = f2bf(sv.y); l.y = f2bf(sv.y - bf2f(h.y));
        h.z = f2bf(sv.z); l.z = f2bf(sv.z - bf2f(h.z));
        h.w = f2bf(sv.w); l.w = f2bf(sv.w - bf2f(h.w));
        *(ushort4*)&Bh[r * 32 + n0] = h;
        *(ushort4*)&Bl[r * 32 + n0] = l;
      }
    }
    __syncthreads();

    short8_t a_hi[4], a_lo[4], b_hi[4], b_lo[4];
#pragma unroll
    for (int i = 0; i < 4; ++i) {
      const int ar = (wm + i * 16 + fm) * 32 + fk;
      a_hi[i] = *(const short8_t*)&Ah[ar];
      a_lo[i] = *(const short8_t*)&Al[ar];
    }
#pragma unroll
    for (int j = 0; j < 4; ++j) {
      const int br = (wn + j * 16 + fm) * 32 + fk;
      b_hi[j] = *(const short8_t*)&Bh[br];
      b_lo[j] = *(const short8_t*)&Bl[br];
    }
#pragma unroll
    for (int i = 0; i < 4; ++i)
#pragma unroll
      for (int j = 0; j < 4; ++j) {
        acc[i][j] = __builtin_amdgcn_mfma_f32_16x16x32_bf16(a_hi[i], b_hi[j], acc[i][j], 0, 0, 0);
        acc[i][j] = __builtin_amdgcn_mfma_f32_16x16x32_bf16(a_lo[i], b_hi[j], acc[i][j], 0, 0, 0);
        acc[i][j] = __builtin_amdgcn_mfma_f32_16x16x32_bf16(a_hi[i], b_lo[j], acc[i][j], 0, 0, 0);
      }
    __syncthreads();
  }

#pragma unroll
  for (int j = 0; j < 4; ++j) {
    const int d = nt * 128 + wn + j * 16 + fm;
#pragma unroll
    for (int i = 0; i < 4; ++i) {
#pragma unroll
      for (int r = 0; r < 4; ++r) {
        const int t = c * CHUNK + wm + i * 16 + (lane >> 4) * 4 + r;
        out[((size_t)t * B_DIM + b) * DV + d] = acc[i][j][r];
      }
    }
  }
}

// ---------------------------------------------------------------------------
extern "C" void kernel_launch(void* const* d_in, const int* in_sizes, int n_in,
                              void* d_out, int out_size, void* d_ws, size_t ws_size,
                              hipStream_t stream)
{
  const float* x  = (const float*)d_in[0];
  const float* Wv = (const float*)d_in[1];
  const float* bv = (const float*)d_in[2];
  const float* Wk = (const float*)d_in[3];
  const float* bk = (const float*)d_in[4];
  const float* Wq = (const float*)d_in[5];
  const float* bq = (const float*)d_in[6];
  const float* Wa = (const float*)d_in[7];
  const float* ba = (const float*)d_in[8];
  float* out = (float*)d_out;

  // ---- workspace layout (same total footprint as proven ~211.35 MB) ----
  // Bt (v^T split-bf16) takes the old v_ws slot: exactly 64 MiB.
  unsigned short* Bt_h = (unsigned short*)d_ws;              // 16,777,216 us
  unsigned short* Bt_l = Bt_h + (size_t)NCH * B_DIM * DV * CHUNK;
  float* k_ws = (float*)(Bt_l + (size_t)NCH * B_DIM * DV * CHUNK); // 2,097,152 f
  float* a_ws = k_ws + (size_t)ROWS * DK;                   //  2,097,152 f
  float* pend = a_ws + (size_t)ROWS * DK;                   //     16,384 f
  float* W_ws = pend + NCH * B_DIM * DK;                    //  8,388,608 f
  float* bcat = W_ws + (size_t)NCH * B_DIM * DV * DK;       //        768 f
  unsigned short* Acat_h = (unsigned short*)(bcat + NPAD);  //  6,291,456 us
  unsigned short* Acat_l = Acat_h + (size_t)NCH * B_DIM * CHUNK * KCAT;
  // x/w staging (read-only during proj; dead afterwards)
  unsigned short* xh = Acat_l + (size_t)NCH * B_DIM * CHUNK * KCAT;  // 16,777,216 us
  unsigned short* xl = xh + (size_t)ROWS * INDIM;           // 16,777,216 us
  unsigned short* wh = xl + (size_t)ROWS * INDIM;           //    393,216 us
  unsigned short* wl = wh + (size_t)NPAD * INDIM;           //    393,216 us

  cast_kernel<<<16384 + 384, 256, 0, stream>>>(
      x, Wv, Wk, Wq, Wa, bv, bk, bq, ba, xh, xl, wh, wl, bcat);
  proj_mfma_kernel<<<dim3(ROWS / 128, NPAD / 128), 256, 0, stream>>>(
      xh, xl, wh, wl, bcat, Bt_h, Bt_l, k_ws, Acat_h, Acat_l, a_ws);
  prep_kernel<<<dim3(NCH, B_DIM), 256, 0, stream>>>(
      a_ws, k_ws, Acat_h, Acat_l, pend);
  wchunk_mfma_kernel<<<dim3(NCH, B_DIM, 4), 256, 0, stream>>>(
      Bt_h, Bt_l, k_ws, pend, W_ws);
  scan_kernel<<<(B_DIM * DV * DK) / 256, 256, 0, stream>>>(W_ws, pend);
  score_mfma_kernel<<<dim3(NCH, B_DIM), 256, 0, stream>>>(
      k_ws, Acat_h, Acat_l);
  out_mfma_kernel<<<dim3(NCH, B_DIM, 4), 256, 0, stream>>>(
      Acat_h, Acat_l, Bt_h, Bt_l, W_ws, out);
}

// Round 7
// 311.246 us; speedup vs baseline: 1.2187x; 1.2187x over previous
//
#include <hip/hip_runtime.h>
#include <math.h>

#define T_DIM 8192
#define B_DIM 4
#define INDIM 512
#define DV 512
#define DK 64
#define CHUNK 128
#define NCH (T_DIM / CHUNK)     // 64
#define ROWS (T_DIM * B_DIM)    // 32768
#define NPAD 768                // 704 proj cols padded to 6x128
#define KCAT 192                // 128 intra + 64 state
#define EPSF 1e-8f

typedef float float4_t __attribute__((ext_vector_type(4)));
typedef short short8_t __attribute__((ext_vector_type(8)));
typedef _Float16 half8_t __attribute__((ext_vector_type(8)));

__device__ inline unsigned short f2bf(float f) {
  unsigned int u = __float_as_uint(f);
  unsigned int r = (u + 0x7fffu + ((u >> 16) & 1u)) >> 16;
  return (unsigned short)r;
}
__device__ inline float bf2f(unsigned short h) {
  return __uint_as_float(((unsigned int)h) << 16);
}
__device__ inline unsigned short f2h(float f) {
  _Float16 h = (_Float16)f;
  unsigned short u;
  __builtin_memcpy(&u, &h, 2);
  return u;
}

__device__ inline void gload16(const void* g, void* l) {
  __builtin_amdgcn_global_load_lds(
      (const __attribute__((address_space(1))) void*)g,
      (__attribute__((address_space(3))) void*)l, 16, 0, 0);
}

// ---------------------------------------------------------------------------
// C0: merged fp16 cast.  blocks [0,16384): x -> xh (fp16).
// blocks [16384,16768): padded concat weights -> wh (fp16) + bcat.
// ---------------------------------------------------------------------------
__global__ __launch_bounds__(256) void cast_kernel(
    const float* __restrict__ x,
    const float* __restrict__ Wv, const float* __restrict__ Wk,
    const float* __restrict__ Wq, const float* __restrict__ Wa,
    const float* __restrict__ bv, const float* __restrict__ bk,
    const float* __restrict__ bq, const float* __restrict__ ba,
    unsigned short* __restrict__ xh, unsigned short* __restrict__ wh,
    float* __restrict__ bcat)
{
  if (blockIdx.x < 16384) {
    const size_t i4 = ((size_t)blockIdx.x * 256 + threadIdx.x) * 4;
    const float4 v = *(const float4*)&x[i4];
    ushort4 h;
    h.x = f2h(v.x); h.y = f2h(v.y); h.z = f2h(v.z); h.w = f2h(v.w);
    *(ushort4*)&xh[i4] = h;
  } else {
    const int t = (blockIdx.x - 16384) * 256 + threadIdx.x;
    const size_t i4 = (size_t)t * 4;
    const int row = (int)(i4 >> 9);
    const int col = (int)(i4 & 511);
    float4 v = {0.f, 0.f, 0.f, 0.f};
    if (row < 512)      v = *(const float4*)&Wv[(size_t)row * INDIM + col];
    else if (row < 576) v = *(const float4*)&Wk[(size_t)(row - 512) * INDIM + col];
    else if (row < 640) v = *(const float4*)&Wq[(size_t)(row - 576) * INDIM + col];
    else if (row < 704) v = *(const float4*)&Wa[(size_t)(row - 640) * INDIM + col];
    ushort4 h;
    h.x = f2h(v.x); h.y = f2h(v.y); h.z = f2h(v.z); h.w = f2h(v.w);
    *(ushort4*)&wh[i4] = h;
    if (t < NPAD) {
      float b = 0.f;
      if (t < 512)      b = bv[t];
      else if (t < 576) b = bk[t - 512];
      else if (t < 640) b = bq[t - 576];
      else if (t < 704) b = ba[t - 640];
      bcat[t] = b;
    }
  }
}

// ---------------------------------------------------------------------------
// K1: fp16 MFMA projection GEMM (M=32768,K=512,N=768), single-term,
// fp32 accumulate.  Epilogue (round-5 proven): v -> v_ws fp32; k -> k_ws
// fp32; q -> Acat cols [128,192) split-bf16; alpha -> a_ws fp32 (sigmoid).
// ---------------------------------------------------------------------------
__global__ __launch_bounds__(256) void proj_mfma_kernel(
    const unsigned short* __restrict__ xh, const unsigned short* __restrict__ wh,
    const float* __restrict__ bcat,
    float* __restrict__ v_ws, float* __restrict__ k_ws,
    unsigned short* __restrict__ Acat_h, unsigned short* __restrict__ Acat_l,
    float* __restrict__ a_ws)
{
  __shared__ __align__(16) _Float16 Ah[128 * 32];
  __shared__ __align__(16) _Float16 Bh[128 * 32];

  const int tid  = threadIdx.x;
  const int r0   = blockIdx.x * 128;
  const int c0   = blockIdx.y * 128;
  const int wave = tid >> 6, lane = tid & 63;
  const int wm   = (wave & 1) * 64, wn = (wave >> 1) * 64;
  const int fm   = lane & 15;
  const int fk   = (lane >> 4) * 8;

  float4_t acc[4][4];
#pragma unroll
  for (int i = 0; i < 4; ++i)
#pragma unroll
    for (int j = 0; j < 4; ++j) acc[i][j] = (float4_t)0.0f;

  const int srow = tid >> 2;           // 0..63
  const int scol = (tid & 3) * 8;      // 0,8,16,24

  for (int k0 = 0; k0 < INDIM; k0 += 32) {
    const size_t ga0 = (size_t)(r0 + srow) * INDIM + k0 + scol;
    const size_t ga1 = (size_t)(r0 + 64 + srow) * INDIM + k0 + scol;
    const size_t gb0 = (size_t)(c0 + srow) * INDIM + k0 + scol;
    const size_t gb1 = (size_t)(c0 + 64 + srow) * INDIM + k0 + scol;
    gload16(&xh[ga0], &Ah[tid * 8]);
    gload16(&xh[ga1], &Ah[(256 + tid) * 8]);
    gload16(&wh[gb0], &Bh[tid * 8]);
    gload16(&wh[gb1], &Bh[(256 + tid) * 8]);
    __syncthreads();

    half8_t a[4], b[4];
#pragma unroll
    for (int i = 0; i < 4; ++i)
      a[i] = *(const half8_t*)&Ah[(wm + i * 16 + fm) * 32 + fk];
#pragma unroll
    for (int j = 0; j < 4; ++j)
      b[j] = *(const half8_t*)&Bh[(wn + j * 16 + fm) * 32 + fk];
#pragma unroll
    for (int i = 0; i < 4; ++i)
#pragma unroll
      for (int j = 0; j < 4; ++j)
        acc[i][j] = __builtin_amdgcn_mfma_f32_16x16x32_f16(a[i], b[j], acc[i][j], 0, 0, 0);
    __syncthreads();
  }

#pragma unroll
  for (int j = 0; j < 4; ++j) {
    const int col = c0 + wn + j * 16 + fm;
    if (col >= 704) continue;
    const float bias = bcat[col];
#pragma unroll
    for (int i = 0; i < 4; ++i) {
#pragma unroll
      for (int r = 0; r < 4; ++r) {
        const int row = r0 + wm + i * 16 + (lane >> 4) * 4 + r;  // row = t*4+b
        const float val = acc[i][j][r] + bias;
        if (col < 512) {
          v_ws[(size_t)row * DV + col] = val;
        } else if (col < 576) {
          k_ws[(size_t)row * DK + col - 512] = val;
        } else if (col < 640) {
          const int tg = row >> 2, bb = row & 3;
          const int cc = tg >> 7, tl = tg & 127;
          const size_t qa = ((size_t)(cc * 4 + bb) * 128 + tl) * KCAT + 128 + (col - 576);
          const unsigned short h = f2bf(val);
          Acat_h[qa] = h;
          Acat_l[qa] = f2bf(val - bf2f(h));
        } else {
          a_ws[(size_t)row * DK + col - 640] = 1.0f / (1.0f + expf(-val));
        }
      }
    }
  }
}

// ---------------------------------------------------------------------------
// K2: per-(c,b) chunk prep.  LDS-resident cumprod, then coalesced
// q_t (Acat hi/lo RMW) and k_t (k_ws fp32 RMW) passes.  grid (NCH, B_DIM).
// ---------------------------------------------------------------------------
__global__ __launch_bounds__(256) void prep_kernel(
    const float* __restrict__ a_ws, float* __restrict__ k_ws,
    unsigned short* __restrict__ Acat_h, unsigned short* __restrict__ Acat_l,
    float* __restrict__ pend)
{
  __shared__ float pal[CHUNK][DK];    // 32 KB: alpha -> cumprod p
  const int c = blockIdx.x, b = blockIdx.y;
  const int cb = c * B_DIM + b;
  const int tid = threadIdx.x;

#pragma unroll
  for (int i = 0; i < 8; ++i) {
    const int f = (i * 256 + tid) * 4;       // 0..8191
    const int t = f >> 6, n0 = f & 63;
    const float4 av = *(const float4*)&a_ws[(size_t)(c * CHUNK + t) * 256 + b * 64 + n0];
    *(float4*)&pal[t][n0] = av;
  }
  __syncthreads();

  if (tid < 64) {
    float p = 1.0f;
#pragma unroll 4
    for (int t = 0; t < CHUNK; ++t) {
      p *= fmaxf(pal[t][tid], EPSF);
      pal[t][tid] = p;
    }
    pend[c * 256 + b * 64 + tid] = p;
  }
  __syncthreads();

#pragma unroll
  for (int i = 0; i < 8; ++i) {
    const int f = (i * 256 + tid) * 4;
    const int t = f >> 6, n0 = f & 63;
    const size_t qa = ((size_t)cb * CHUNK + t) * KCAT + 128 + n0;
    ushort4 qh = *(const ushort4*)&Acat_h[qa];
    ushort4 ql = *(const ushort4*)&Acat_l[qa];
    float q0 = (bf2f(qh.x) + bf2f(ql.x)) * pal[t][n0 + 0];
    float q1 = (bf2f(qh.y) + bf2f(ql.y)) * pal[t][n0 + 1];
    float q2 = (bf2f(qh.z) + bf2f(ql.z)) * pal[t][n0 + 2];
    float q3 = (bf2f(qh.w) + bf2f(ql.w)) * pal[t][n0 + 3];
    ushort4 h, l;
    h.x = f2bf(q0); l.x = f2bf(q0 - bf2f(h.x));
    h.y = f2bf(q1); l.y = f2bf(q1 - bf2f(h.y));
    h.z = f2bf(q2); l.z = f2bf(q2 - bf2f(h.z));
    h.w = f2bf(q3); l.w = f2bf(q3 - bf2f(h.w));
    *(ushort4*)&Acat_h[qa] = h;
    *(ushort4*)&Acat_l[qa] = l;
  }

#pragma unroll
  for (int i = 0; i < 8; ++i) {
    const int f = (i * 256 + tid) * 4;
    const int t = f >> 6, n0 = f & 63;
    const size_t ka = (size_t)(c * CHUNK + t) * 256 + b * 64 + n0;
    float4 kv = *(const float4*)&k_ws[ka];
    kv.x = kv.x / (pal[t][n0 + 0] + EPSF);
    kv.y = kv.y / (pal[t][n0 + 1] + EPSF);
    kv.z = kv.z / (pal[t][n0 + 2] + EPSF);
    kv.w = kv.w / (pal[t][n0 + 3] + EPSF);
    *(float4*)&k_ws[ka] = kv;
  }
}

// ---------------------------------------------------------------------------
// K4b: transpose-cast v -> Bt hi/lo, layout [(c,b)][d][s] bf16.  (round-5)
// ---------------------------------------------------------------------------
__global__ __launch_bounds__(256) void vt_kernel(
    const float* __restrict__ v_ws,
    unsigned short* __restrict__ Bt_h, unsigned short* __restrict__ Bt_l)
{
  __shared__ float Ts[CHUNK][65];
  const int c = blockIdx.x, b = blockIdx.y, dblk = blockIdx.z;
  const int cb = c * B_DIM + b;
  const int d0 = dblk * 64;
  const int tid = threadIdx.x;
#pragma unroll
  for (int q = 0; q < 8; ++q) {
    const int idx = (q * 256 + tid) * 4;       // 0..8191
    const int s = idx >> 6, dd = idx & 63;
    const float4 v = *(const float4*)&v_ws[(size_t)((c * CHUNK + s) * B_DIM + b) * DV + d0 + dd];
    Ts[s][dd + 0] = v.x; Ts[s][dd + 1] = v.y;
    Ts[s][dd + 2] = v.z; Ts[s][dd + 3] = v.w;
  }
  __syncthreads();
#pragma unroll
  for (int q = 0; q < 8; ++q) {
    const int idx = (q * 256 + tid) * 4;
    const int dd = idx >> 7, s0 = idx & 127;
    float v0 = Ts[s0 + 0][dd], v1 = Ts[s0 + 1][dd];
    float v2 = Ts[s0 + 2][dd], v3 = Ts[s0 + 3][dd];
    ushort4 h, l;
    h.x = f2bf(v0); l.x = f2bf(v0 - bf2f(h.x));
    h.y = f2bf(v1); l.y = f2bf(v1 - bf2f(h.y));
    h.z = f2bf(v2); l.z = f2bf(v2 - bf2f(h.z));
    h.w = f2bf(v3); l.w = f2bf(v3 - bf2f(h.w));
    const size_t oa = ((size_t)cb * DV + d0 + dd) * CHUNK + s0;
    *(ushort4*)&Bt_h[oa] = h;
    *(ushort4*)&Bt_l[oa] = l;
  }
}

// ---------------------------------------------------------------------------
// K3: wchunk via MFMA.  W[d][n] = (sum_t v^T[d][t]*k_t[t][n]) * pend[n].
// ---------------------------------------------------------------------------
__global__ __launch_bounds__(256) void wchunk_mfma_kernel(
    const unsigned short* __restrict__ Bt_h, const unsigned short* __restrict__ Bt_l,
    const float* __restrict__ k_ws, const float* __restrict__ pend,
    float* __restrict__ W_ws)
{
  __shared__ __align__(16) unsigned short Ah[128 * 32];
  __shared__ __align__(16) unsigned short Al[128 * 32];

  const int c = blockIdx.x, b = blockIdx.y, dt = blockIdx.z;
  const int cb = c * B_DIM + b;
  const int tid  = threadIdx.x;
  const int wave = tid >> 6, lane = tid & 63;
  const int wm   = (wave & 1) * 64;
  const int wn   = (wave >> 1) * 32;
  const int fm   = lane & 15;
  const int fk   = (lane >> 4) * 8;

  const unsigned short* Ab_h = Bt_h + ((size_t)cb * DV + dt * 128) * CHUNK;
  const unsigned short* Ab_l = Bt_l + ((size_t)cb * DV + dt * 128) * CHUNK;

  float4_t acc[4][2];
#pragma unroll
  for (int i = 0; i < 4; ++i)
#pragma unroll
    for (int j = 0; j < 2; ++j) acc[i][j] = (float4_t)0.0f;

  for (int ks = 0; ks < 4; ++ks) {
    const int k0 = ks * 32;
#pragma unroll
    for (int q = 0; q < 2; ++q) {
      const int flat = (q * 256 + tid) * 8;
      const int row = flat >> 5, col = flat & 31;
      gload16(&Ab_h[(size_t)row * CHUNK + k0 + col], &Ah[flat]);
      gload16(&Ab_l[(size_t)row * CHUNK + k0 + col], &Al[flat]);
    }

    short8_t b_hi[2], b_lo[2];
#pragma unroll
    for (int j = 0; j < 2; ++j) {
      const int n = wn + j * 16 + fm;
#pragma unroll
      for (int e = 0; e < 8; ++e) {
        const float kv = k_ws[(size_t)(c * CHUNK + k0 + fk + e) * 256 + b * 64 + n];
        const unsigned short h = f2bf(kv);
        b_hi[j][e] = (short)h;
        b_lo[j][e] = (short)f2bf(kv - bf2f(h));
      }
    }
    __syncthreads();

    short8_t a_hi[4], a_lo[4];
#pragma unroll
    for (int i = 0; i < 4; ++i) {
      const int ar = (wm + i * 16 + fm) * 32 + fk;
      a_hi[i] = *(const short8_t*)&Ah[ar];
      a_lo[i] = *(const short8_t*)&Al[ar];
    }
#pragma unroll
    for (int i = 0; i < 4; ++i)
#pragma unroll
      for (int j = 0; j < 2; ++j) {
        acc[i][j] = __builtin_amdgcn_mfma_f32_16x16x32_bf16(a_hi[i], b_hi[j], acc[i][j], 0, 0, 0);
        acc[i][j] = __builtin_amdgcn_mfma_f32_16x16x32_bf16(a_lo[i], b_hi[j], acc[i][j], 0, 0, 0);
        acc[i][j] = __builtin_amdgcn_mfma_f32_16x16x32_bf16(a_hi[i], b_lo[j], acc[i][j], 0, 0, 0);
      }
    __syncthreads();
  }

#pragma unroll
  for (int j = 0; j < 2; ++j) {
    const int n = wn + j * 16 + fm;
    const float pj = pend[c * 256 + b * 64 + n];
#pragma unroll
    for (int i = 0; i < 4; ++i) {
#pragma unroll
      for (int r = 0; r < 4; ++r) {
        const int d = dt * 128 + wm + i * 16 + (lane >> 4) * 4 + r;
        W_ws[((size_t)cb * DV + d) * DK + n] = acc[i][j][r] * pj;
      }
    }
  }
}

// ---------------------------------------------------------------------------
// K4: sequential state scan over chunks (in place; W_ws[c] <- S_c pre-update)
// ---------------------------------------------------------------------------
__global__ __launch_bounds__(256) void scan_kernel(
    float* __restrict__ W_ws, const float* __restrict__ pend)
{
  const int flat = blockIdx.x * 256 + threadIdx.x;
  const int n = flat & 63;
  const int bd = flat >> 6;
  const int b = bd >> 9;
  float s = 0.0f;
  for (int c = 0; c < NCH; ++c) {
    const int off = c * 131072 + flat;
    const float w = W_ws[off];
    W_ws[off] = s;
    s = s * pend[c * 256 + b * 64 + n] + w;
  }
}

// ---------------------------------------------------------------------------
// K5: A = tril(q_t @ k_t^T) via MFMA.  Writes Acat cols [0,128) hi/lo.
// ---------------------------------------------------------------------------
__global__ __launch_bounds__(256) void score_mfma_kernel(
    const float* __restrict__ k_ws,
    unsigned short* __restrict__ Acat_h, unsigned short* __restrict__ Acat_l)
{
  __shared__ __align__(16) unsigned short Ah[128 * 32];
  __shared__ __align__(16) unsigned short Al[128 * 32];
  __shared__ __align__(16) unsigned short Bh[128 * 32];
  __shared__ __align__(16) unsigned short Bl[128 * 32];

  const int c = blockIdx.x, b = blockIdx.y;
  const int cb = c * B_DIM + b;
  const int tid  = threadIdx.x;
  const int wave = tid >> 6, lane = tid & 63;
  const int wm   = (wave & 1) * 64, wn = (wave >> 1) * 64;
  const int fm   = lane & 15;
  const int fk   = (lane >> 4) * 8;

  const unsigned short* Aq_h = Acat_h + (size_t)cb * CHUNK * KCAT + 128;
  const unsigned short* Aq_l = Acat_l + (size_t)cb * CHUNK * KCAT + 128;

  float4_t acc[4][4];
#pragma unroll
  for (int i = 0; i < 4; ++i)
#pragma unroll
    for (int j = 0; j < 4; ++j) acc[i][j] = (float4_t)0.0f;

  for (int ks = 0; ks < 2; ++ks) {
    const int k0 = ks * 32;
#pragma unroll
    for (int q = 0; q < 2; ++q) {
      const int flat = (q * 256 + tid) * 8;
      const int row = flat >> 5, col = flat & 31;
      gload16(&Aq_h[(size_t)row * KCAT + k0 + col], &Ah[flat]);
      gload16(&Aq_l[(size_t)row * KCAT + k0 + col], &Al[flat]);
    }
#pragma unroll
    for (int q = 0; q < 4; ++q) {
      const int flat = (q * 256 + tid) * 4;
      const int s = flat >> 5, n0 = flat & 31;
      const float4 kv = *(const float4*)&k_ws[(size_t)(c * CHUNK + s) * 256 + b * 64 + k0 + n0];
      ushort4 h, l;
      h.x = f2bf(kv.x); l.x = f2bf(kv.x - bf2f(h.x));
      h.y = f2bf(kv.y); l.y = f2bf(kv.y - bf2f(h.y));
      h.z = f2bf(kv.z); l.z = f2bf(kv.z - bf2f(h.z));
      h.w = f2bf(kv.w); l.w = f2bf(kv.w - bf2f(h.w));
      *(ushort4*)&Bh[s * 32 + n0] = h;
      *(ushort4*)&Bl[s * 32 + n0] = l;
    }
    __syncthreads();

    short8_t a_hi[4], a_lo[4], b_hi[4], b_lo[4];
#pragma unroll
    for (int i = 0; i < 4; ++i) {
      const int ar = (wm + i * 16 + fm) * 32 + fk;
      a_hi[i] = *(const short8_t*)&Ah[ar];
      a_lo[i] = *(const short8_t*)&Al[ar];
    }
#pragma unroll
    for (int j = 0; j < 4; ++j) {
      const int br = (wn + j * 16 + fm) * 32 + fk;
      b_hi[j] = *(const short8_t*)&Bh[br];
      b_lo[j] = *(const short8_t*)&Bl[br];
    }
#pragma unroll
    for (int i = 0; i < 4; ++i)
#pragma unroll
      for (int j = 0; j < 4; ++j) {
        acc[i][j] = __builtin_amdgcn_mfma_f32_16x16x32_bf16(a_hi[i], b_hi[j], acc[i][j], 0, 0, 0);
        acc[i][j] = __builtin_amdgcn_mfma_f32_16x16x32_bf16(a_lo[i], b_hi[j], acc[i][j], 0, 0, 0);
        acc[i][j] = __builtin_amdgcn_mfma_f32_16x16x32_bf16(a_hi[i], b_lo[j], acc[i][j], 0, 0, 0);
      }
    __syncthreads();
  }

#pragma unroll
  for (int j = 0; j < 4; ++j) {
    const int s = wn + j * 16 + fm;
#pragma unroll
    for (int i = 0; i < 4; ++i) {
#pragma unroll
      for (int r = 0; r < 4; ++r) {
        const int t = wm + i * 16 + (lane >> 4) * 4 + r;
        const float vv = (s <= t) ? acc[i][j][r] : 0.0f;
        const unsigned short h = f2bf(vv);
        const size_t oa = ((size_t)cb * CHUNK + t) * KCAT + s;
        Acat_h[oa] = h;
        Acat_l[oa] = f2bf(vv - bf2f(h));
      }
    }
  }
}

// ---------------------------------------------------------------------------
// K6: y = [A|q_t] @ [v ; S^T]  via split-bf16 MFMA.  M=128(t) N=128(d-tile)
// K=192.  Steps 0..3 stage B from Bt; steps 4,5 convert S fp32.
// ---------------------------------------------------------------------------
__global__ __launch_bounds__(256) void out_mfma_kernel(
    const unsigned short* __restrict__ Acat_h, const unsigned short* __restrict__ Acat_l,
    const unsigned short* __restrict__ Bt_h, const unsigned short* __restrict__ Bt_l,
    const float* __restrict__ W_ws, float* __restrict__ out)
{
  __shared__ __align__(16) unsigned short Ah[128 * 32];
  __shared__ __align__(16) unsigned short Al[128 * 32];
  __shared__ __align__(16) unsigned short Bh[128 * 32];
  __shared__ __align__(16) unsigned short Bl[128 * 32];

  const int c = blockIdx.x, b = blockIdx.y, nt = blockIdx.z;
  const int cb = c * B_DIM + b;
  const int tid  = threadIdx.x;
  const int wave = tid >> 6, lane = tid & 63;
  const int wm   = (wave & 1) * 64, wn = (wave >> 1) * 64;
  const int fm   = lane & 15;
  const int fk   = (lane >> 4) * 8;

  const unsigned short* Ab_h = Acat_h + (size_t)cb * CHUNK * KCAT;
  const unsigned short* Ab_l = Acat_l + (size_t)cb * CHUNK * KCAT;
  const unsigned short* Bb_h = Bt_h + ((size_t)cb * DV + nt * 128) * CHUNK;
  const unsigned short* Bb_l = Bt_l + ((size_t)cb * DV + nt * 128) * CHUNK;
  const float* Sb = W_ws + ((size_t)cb * DV + nt * 128) * DK;

  float4_t acc[4][4];
#pragma unroll
  for (int i = 0; i < 4; ++i)
#pragma unroll
    for (int j = 0; j < 4; ++j) acc[i][j] = (float4_t)0.0f;

  for (int ks = 0; ks < 6; ++ks) {
    const int k0 = ks * 32;
#pragma unroll
    for (int q = 0; q < 2; ++q) {
      const int flat = q * 2048 + tid * 8;
      const int row = flat >> 5, col = flat & 31;
      gload16(&Ab_h[(size_t)row * KCAT + k0 + col], &Ah[flat]);
      gload16(&Ab_l[(size_t)row * KCAT + k0 + col], &Al[flat]);
    }
    if (ks < 4) {
#pragma unroll
      for (int q = 0; q < 2; ++q) {
        const int flat = q * 2048 + tid * 8;
        const int row = flat >> 5, col = flat & 31;
        gload16(&Bb_h[(size_t)row * CHUNK + k0 + col], &Bh[flat]);
        gload16(&Bb_l[(size_t)row * CHUNK + k0 + col], &Bl[flat]);
      }
    } else {
#pragma unroll
      for (int q = 0; q < 4; ++q) {
        const int flat = (q * 256 + tid) * 4;
        const int r = flat >> 5, n0 = flat & 31;
        const float4 sv = *(const float4*)&Sb[(size_t)r * DK + (k0 - 128) + n0];
        ushort4 h, l;
        h.x = f2bf(sv.x); l.x = f2bf(sv.x - bf2f(h.x));
        h.y = f2bf(sv.y); l.y = f2bf(sv.y - bf2f(h.y));
        h.z = f2bf(sv.z); l.z = f2bf(sv.z - bf2f(h.z));
        h.w = f2bf(sv.w); l.w = f2bf(sv.w - bf2f(h.w));
        *(ushort4*)&Bh[r * 32 + n0] = h;
        *(ushort4*)&Bl[r * 32 + n0] = l;
      }
    }
    __syncthreads();

    short8_t a_hi[4], a_lo[4], b_hi[4], b_lo[4];
#pragma unroll
    for (int i = 0; i < 4; ++i) {
      const int ar = (wm + i * 16 + fm) * 32 + fk;
      a_hi[i] = *(const short8_t*)&Ah[ar];
      a_lo[i] = *(const short8_t*)&Al[ar];
    }
#pragma unroll
    for (int j = 0; j < 4; ++j) {
      const int br = (wn + j * 16 + fm) * 32 + fk;
      b_hi[j] = *(const short8_t*)&Bh[br];
      b_lo[j] = *(const short8_t*)&Bl[br];
    }
#pragma unroll
    for (int i = 0; i < 4; ++i)
#pragma unroll
      for (int j = 0; j < 4; ++j) {
        acc[i][j] = __builtin_amdgcn_mfma_f32_16x16x32_bf16(a_hi[i], b_hi[j], acc[i][j], 0, 0, 0);
        acc[i][j] = __builtin_amdgcn_mfma_f32_16x16x32_bf16(a_lo[i], b_hi[j], acc[i][j], 0, 0, 0);
        acc[i][j] = __builtin_amdgcn_mfma_f32_16x16x32_bf16(a_hi[i], b_lo[j], acc[i][j], 0, 0, 0);
      }
    __syncthreads();
  }

#pragma unroll
  for (int j = 0; j < 4; ++j) {
    const int d = nt * 128 + wn + j * 16 + fm;
#pragma unroll
    for (int i = 0; i < 4; ++i) {
#pragma unroll
      for (int r = 0; r < 4; ++r) {
        const int t = c * CHUNK + wm + i * 16 + (lane >> 4) * 4 + r;
        out[((size_t)t * B_DIM + b) * DV + d] = acc[i][j][r];
      }
    }
  }
}

// ---------------------------------------------------------------------------
extern "C" void kernel_launch(void* const* d_in, const int* in_sizes, int n_in,
                              void* d_out, int out_size, void* d_ws, size_t ws_size,
                              hipStream_t stream)
{
  const float* x  = (const float*)d_in[0];
  const float* Wv = (const float*)d_in[1];
  const float* bv = (const float*)d_in[2];
  const float* Wk = (const float*)d_in[3];
  const float* bk = (const float*)d_in[4];
  const float* Wq = (const float*)d_in[5];
  const float* bq = (const float*)d_in[6];
  const float* Wa = (const float*)d_in[7];
  const float* ba = (const float*)d_in[8];
  float* out = (float*)d_out;

  // ---- workspace layout (~176 MB, within the proven 211 MB budget) ----
  float* ws   = (float*)d_ws;
  float* v_ws = ws;                                         // 16,777,216 f
  float* k_ws = v_ws + (size_t)ROWS * DV;                   //  2,097,152 f
  float* a_ws = k_ws + (size_t)ROWS * DK;                   //  2,097,152 f
  float* pend = a_ws + (size_t)ROWS * DK;                   //     16,384 f
  float* W_ws = pend + NCH * B_DIM * DK;                    //  8,388,608 f
  float* bcat = W_ws + (size_t)NCH * B_DIM * DV * DK;       //        768 f
  unsigned short* Acat_h = (unsigned short*)(bcat + NPAD);  //  6,291,456 us
  unsigned short* Acat_l = Acat_h + (size_t)NCH * B_DIM * CHUNK * KCAT;
  unsigned short* uni = Acat_l + (size_t)NCH * B_DIM * CHUNK * KCAT;
  // union A: fp16 proj staging (dead after proj_mfma)
  unsigned short* xh = uni;                                 // 16,777,216 us
  unsigned short* wh = xh + (size_t)ROWS * INDIM;           //    393,216 us
  // union B: v^T split-bf16 (written by vt_kernel after proj) — 64 MiB
  unsigned short* Bt_h = uni;
  unsigned short* Bt_l = Bt_h + (size_t)NCH * B_DIM * DV * CHUNK;

  cast_kernel<<<16384 + 384, 256, 0, stream>>>(
      x, Wv, Wk, Wq, Wa, bv, bk, bq, ba, xh, wh, bcat);
  proj_mfma_kernel<<<dim3(ROWS / 128, NPAD / 128), 256, 0, stream>>>(
      xh, wh, bcat, v_ws, k_ws, Acat_h, Acat_l, a_ws);
  vt_kernel<<<dim3(NCH, B_DIM, 8), 256, 0, stream>>>(v_ws, Bt_h, Bt_l);
  prep_kernel<<<dim3(NCH, B_DIM), 256, 0, stream>>>(
      a_ws, k_ws, Acat_h, Acat_l, pend);
  wchunk_mfma_kernel<<<dim3(NCH, B_DIM, 4), 256, 0, stream>>>(
      Bt_h, Bt_l, k_ws, pend, W_ws);
  scan_kernel<<<(B_DIM * DV * DK) / 256, 256, 0, stream>>>(W_ws, pend);
  score_mfma_kernel<<<dim3(NCH, B_DIM), 256, 0, stream>>>(
      k_ws, Acat_h, Acat_l);
  out_mfma_kernel<<<dim3(NCH, B_DIM, 4), 256, 0, stream>>>(
      Acat_h, Acat_l, Bt_h, Bt_l, W_ws, out);
}